// Round 1
// baseline (830.254 us; speedup 1.0000x reference)
//
#include <hip/hip_runtime.h>
#include <hip/hip_bf16.h>
#include <cstdint>
#include <cstddef>

using u16 = unsigned short;
using u32 = unsigned int;

typedef __attribute__((ext_vector_type(8))) __bf16 bf16x8;
typedef __attribute__((ext_vector_type(4))) float f32x4;
typedef __attribute__((ext_vector_type(2))) float f32x2;
typedef __attribute__((ext_vector_type(4))) u32 u32x4;

typedef const __attribute__((address_space(1))) void* gas_ptr;
typedef __attribute__((address_space(3))) void* las_ptr;

__device__ __forceinline__ void async_cp16(const void* g, void* l) {
  __builtin_amdgcn_global_load_lds((gas_ptr)g, (las_ptr)l, 16, 0, 0);
}

__device__ __forceinline__ float bf2f(u16 u) {
  u32 v = ((u32)u) << 16;
  return __builtin_bit_cast(float, v);
}
__device__ __forceinline__ u16 f2bf(float f) {
  u32 v = __builtin_bit_cast(u32, f);
  u32 r = (v + 0x7fffu + ((v >> 16) & 1u)) >> 16;  // RNE
  return (u16)r;
}

__device__ __forceinline__ f32x4 mfma16(bf16x8 a, bf16x8 b, f32x4 c) {
  return __builtin_amdgcn_mfma_f32_16x16x32_bf16(a, b, c, 0, 0, 0);
}

// ---------------------------------------------------------------- convert
__global__ __launch_bounds__(256) void cvt_f32_bf16(const float* __restrict__ in,
                                                    u16* __restrict__ out, int n8) {
  int i = blockIdx.x * blockDim.x + threadIdx.x;
  int stride = gridDim.x * blockDim.x;
  for (; i < n8; i += stride) {
    const float4* p = (const float4*)(in + (size_t)i * 8);
    float4 a = p[0], b = p[1];
    union { u16 us[8]; u32x4 v; } o;
    o.us[0] = f2bf(a.x); o.us[1] = f2bf(a.y); o.us[2] = f2bf(a.z); o.us[3] = f2bf(a.w);
    o.us[4] = f2bf(b.x); o.us[5] = f2bf(b.y); o.us[6] = f2bf(b.z); o.us[7] = f2bf(b.w);
    *(u32x4*)(out + (size_t)i * 8) = o.v;
  }
}

// ---------------------------------------------------------------- GEMM C = A * B^T
// A: MxK bf16 row-major, B: NxK bf16 row-major (i.e. B^T supplied), C: MxN.
// m97 structure: 128x128 block tile, 4 waves (2x2 of 64x64), BK=32,
// global_load_lds width=16 staging, XOR swizzle sigma(row)=(row>>1)&3.
template <bool F32OUT>
__global__ __launch_bounds__(256) void gemm_bt(const u16* __restrict__ A,
                                               const u16* __restrict__ B,
                                               void* __restrict__ Cv,
                                               int M, int N, int K) {
  __shared__ __align__(16) u16 As[128 * 32];
  __shared__ __align__(16) u16 Bs[128 * 32];
  const int tid = threadIdx.x;
  const int wave = tid >> 6, lane = tid & 63;
  const int quad = lane >> 4, c16 = lane & 15;
  const int m0 = blockIdx.y * 128, n0 = blockIdx.x * 128;
  const int wm = (wave & 1) * 64, wn = (wave >> 1) * 64;

  f32x4 acc[4][4] = {};

  // staging: chunk c in [0,512): row=c>>2, stored seg=c&3,
  // fetched global seg = (c&3) ^ ((c>>3)&3)   [sigma(row)=(row>>1)&3]
  const int arow = tid >> 2;
  const int aseg = (tid & 3) ^ ((tid >> 3) & 3);
  const u16* Ab = A + (size_t)m0 * K;
  const u16* Bb = B + (size_t)n0 * K;

  for (int k0 = 0; k0 < K; k0 += 32) {
    __syncthreads();
    async_cp16(Ab + (size_t)arow * K + k0 + aseg * 8, As + (size_t)tid * 8);
    async_cp16(Ab + (size_t)(arow + 64) * K + k0 + aseg * 8, As + (size_t)(tid + 256) * 8);
    async_cp16(Bb + (size_t)arow * K + k0 + aseg * 8, Bs + (size_t)tid * 8);
    async_cp16(Bb + (size_t)(arow + 64) * K + k0 + aseg * 8, Bs + (size_t)(tid + 256) * 8);
    asm volatile("s_waitcnt vmcnt(0)" ::: "memory");
    __syncthreads();

    bf16x8 af[4], bfr[4];
#pragma unroll
    for (int mt = 0; mt < 4; ++mt) {
      int row = wm + mt * 16 + c16;
      int slot = row * 4 + (quad ^ ((row >> 1) & 3));
      af[mt] = *(const bf16x8*)(As + slot * 8);
    }
#pragma unroll
    for (int nt = 0; nt < 4; ++nt) {
      int row = wn + nt * 16 + c16;
      int slot = row * 4 + (quad ^ ((row >> 1) & 3));
      bfr[nt] = *(const bf16x8*)(Bs + slot * 8);
    }
#pragma unroll
    for (int mt = 0; mt < 4; ++mt)
#pragma unroll
      for (int nt = 0; nt < 4; ++nt)
        acc[mt][nt] = mfma16(af[mt], bfr[nt], acc[mt][nt]);
  }

  // epilogue: C/D layout col=lane&15, row=quad*4+reg
#pragma unroll
  for (int mt = 0; mt < 4; ++mt) {
#pragma unroll
    for (int nt = 0; nt < 4; ++nt) {
#pragma unroll
      for (int r = 0; r < 4; ++r) {
        int gm = m0 + wm + mt * 16 + quad * 4 + r;
        int gn = n0 + wn + nt * 16 + c16;
        float v = acc[mt][nt][r];
        if (F32OUT)
          ((float*)Cv)[(size_t)gm * N + gn] = v;
        else
          ((u16*)Cv)[(size_t)gm * N + gn] = f2bf(v);
      }
    }
  }
}

// ---------------------------------------------------------------- RoPE + RMSNorm
// in: (s, n_heads*128) bf16; out: (n_heads, 2048, 128) bf16 head-major.
__global__ __launch_bounds__(256) void rope_rms(const u16* __restrict__ in,
                                                u16* __restrict__ out,
                                                const float* __restrict__ freqs,
                                                int n_heads) {
  int gw = blockIdx.x * 4 + (threadIdx.x >> 6);
  int lane = threadIdx.x & 63;
  int s = gw / n_heads, h = gw % n_heads;
  u32 ab = *(const u32*)(in + ((size_t)s * n_heads + h) * 128 + lane * 2);
  float a = bf2f((u16)(ab & 0xffff));
  float b = bf2f((u16)(ab >> 16));
  f32x2 ff = *(const f32x2*)(freqs + (size_t)s * 128 + lane * 2);
  float ra = a * ff.x - b * ff.y;
  float rb = a * ff.y + b * ff.x;
  float ss = ra * ra + rb * rb;
#pragma unroll
  for (int m = 32; m; m >>= 1) ss += __shfl_xor(ss, m, 64);
  float r = rsqrtf(ss * (1.0f / 128.0f) + 1e-5f);
  u32 pk = (u32)f2bf(ra * r) | ((u32)f2bf(rb * r) << 16);
  *(u32*)(out + ((size_t)h * 2048 + s) * 128 + lane * 2) = pk;
}

// ---------------------------------------------------------------- flash attention
// Q: (32, 2048, 128) bf16; Kh: (8, 2048, 128) bf16; VT: (8*128, 2048) bf16.
// O: (2048, 4096) bf16 (s, h*128+d). Causal, scale=1/sqrt(128), GQA rep=4.
#define SEQ 2048
__global__ __launch_bounds__(256) void attn(const u16* __restrict__ Q,
                                            const u16* __restrict__ Kh,
                                            const u16* __restrict__ VT,
                                            u16* __restrict__ O) {
  __shared__ __align__(16) u16 Ks[32 * 128];    // K tile, swizzled seg^(t&7)
  __shared__ __align__(16) u16 Vs[128 * 32];    // VT tile, swizzled seg^((d>>1)&3)
  __shared__ __align__(16) u16 Ps[4][16 * 32];  // per-wave P, swizzled
  const int tid = threadIdx.x;
  const int wave = tid >> 6, lane = tid & 63;
  const int quad = lane >> 4, c16 = lane & 15;
  const int qb = gridDim.x - 1 - blockIdx.x;  // heavy blocks dispatch first
  const int h = blockIdx.y;
  const int hk = h >> 2;
  const int q0 = qb * 64 + wave * 16;

  // Q A-fragments: A[m=c16][k=quad*8+j], 4 k-chunks of 32
  bf16x8 qf[4];
  const u16* qbase = Q + ((size_t)h * SEQ + q0 + c16) * 128;
#pragma unroll
  for (int c = 0; c < 4; ++c) qf[c] = *(const bf16x8*)(qbase + c * 32 + quad * 8);

  f32x4 o_acc[8] = {};
  float mrow[4], lrow[4];
#pragma unroll
  for (int r = 0; r < 4; ++r) { mrow[r] = -3.0e38f; lrow[r] = 0.f; }

  const float sc = 0.08838834764831845f * 1.4426950408889634f;  // rsqrt(128)*log2(e)
  const int t_end = qb * 64 + 64;
  const u16* Kb = Kh + (size_t)hk * SEQ * 128;
  const u16* Vb = VT + (size_t)hk * 128 * SEQ;

  const int kr0 = tid >> 4, ks0 = (tid & 15) ^ (kr0 & 7);
  const int kr1 = (tid + 256) >> 4, ks1 = ((tid + 256) & 15) ^ (kr1 & 7);
  const int vr0 = tid >> 2, vs0 = (tid & 3) ^ ((tid >> 3) & 3);

  for (int t0 = 0; t0 < t_end; t0 += 32) {
    __syncthreads();
    async_cp16(Kb + (size_t)(t0 + kr0) * 128 + ks0 * 8, Ks + (size_t)tid * 8);
    async_cp16(Kb + (size_t)(t0 + kr1) * 128 + ks1 * 8, Ks + (size_t)(tid + 256) * 8);
    async_cp16(Vb + (size_t)vr0 * SEQ + t0 + vs0 * 8, Vs + (size_t)tid * 8);
    async_cp16(Vb + (size_t)(vr0 + 64) * SEQ + t0 + vs0 * 8, Vs + (size_t)(tid + 256) * 8);
    asm volatile("s_waitcnt vmcnt(0)" ::: "memory");
    __syncthreads();

    // scores: two 16x16 col tiles
    f32x4 s_acc[2] = {};
#pragma unroll
    for (int ct = 0; ct < 2; ++ct) {
#pragma unroll
      for (int c = 0; c < 4; ++c) {
        int t = ct * 16 + c16;
        int seg = c * 4 + quad;
        int slot = t * 16 + (seg ^ (t & 7));
        bf16x8 kf = *(const bf16x8*)(Ks + slot * 8);
        s_acc[ct] = mfma16(qf[c], kf, s_acc[ct]);
      }
    }

    // online softmax (C layout: row=quad*4+r, col=c16)
    float pv[2][4];
#pragma unroll
    for (int r = 0; r < 4; ++r) {
      int s_idx = q0 + quad * 4 + r;
      float mx = -3.0e38f;
#pragma unroll
      for (int ct = 0; ct < 2; ++ct) {
        int t_idx = t0 + ct * 16 + c16;
        float v = (t_idx <= s_idx) ? s_acc[ct][r] * sc : -1.0e30f;
        pv[ct][r] = v;
        mx = fmaxf(mx, v);
      }
#pragma unroll
      for (int m = 1; m < 16; m <<= 1) mx = fmaxf(mx, __shfl_xor(mx, m, 64));
      float newm = fmaxf(mrow[r], mx);
      float rsum = 0.f;
#pragma unroll
      for (int ct = 0; ct < 2; ++ct) {
        float p = exp2f(pv[ct][r] - newm);
        pv[ct][r] = p;
        rsum += p;
      }
#pragma unroll
      for (int m = 1; m < 16; m <<= 1) rsum += __shfl_xor(rsum, m, 64);
      float alpha = exp2f(mrow[r] - newm);
      lrow[r] = lrow[r] * alpha + rsum;
      mrow[r] = newm;
#pragma unroll
      for (int nt = 0; nt < 8; ++nt) o_acc[nt][r] *= alpha;
    }

    // P -> LDS (bf16, swizzled), then read back as A-fragment
#pragma unroll
    for (int ct = 0; ct < 2; ++ct) {
#pragma unroll
      for (int r = 0; r < 4; ++r) {
        int row = quad * 4 + r;
        int col = ct * 16 + c16;
        int sseg = (col >> 3) ^ ((row >> 1) & 3);
        Ps[wave][row * 32 + sseg * 8 + (col & 7)] = f2bf(pv[ct][r]);
      }
    }
    asm volatile("s_waitcnt lgkmcnt(0)" ::: "memory");
    int pslot = c16 * 4 + (quad ^ ((c16 >> 1) & 3));
    bf16x8 pf = *(const bf16x8*)(&Ps[wave][pslot * 8]);

    // O += P * V : B[k=t][n=d] from swizzled VT tile
#pragma unroll
    for (int nt = 0; nt < 8; ++nt) {
      int dl = nt * 16 + c16;
      int vslot = dl * 4 + (quad ^ ((dl >> 1) & 3));
      bf16x8 vf = *(const bf16x8*)(Vs + vslot * 8);
      o_acc[nt] = mfma16(pf, vf, o_acc[nt]);
    }
  }

  // epilogue: O /= l, store (s, h*128+d) bf16
#pragma unroll
  for (int r = 0; r < 4; ++r) {
    float inv = 1.0f / lrow[r];
    int s_idx = q0 + quad * 4 + r;
    u16* ob = O + (size_t)s_idx * 4096 + (size_t)h * 128;
#pragma unroll
    for (int nt = 0; nt < 8; ++nt) ob[nt * 16 + c16] = f2bf(o_acc[nt][r] * inv);
  }
}

// ---------------------------------------------------------------- launch
extern "C" void kernel_launch(void* const* d_in, const int* in_sizes, int n_in,
                              void* d_out, int out_size, void* d_ws, size_t ws_size,
                              hipStream_t stream) {
  const float* x  = (const float*)d_in[0];
  const float* wq = (const float*)d_in[1];
  const float* wk = (const float*)d_in[2];
  const float* wv = (const float*)d_in[3];
  const float* wo = (const float*)d_in[4];
  const float* fr = (const float*)d_in[5];
  float* out = (float*)d_out;

  const size_t S = 2048, D = 4096, KV = 1024;
  u16* p = (u16*)d_ws;
  u16* xb   = p; p += S * D;       // x bf16
  u16* wqb  = p; p += D * D;       // wq bf16 (later reused for wo)
  u16* wkb  = p; p += KV * D;
  u16* wvb  = p; p += KV * D;
  u16* qraw = p; p += S * D;       // Q gemm out (later reused for attn out)
  u16* kraw = p; p += S * KV;
  u16* vt   = p; p += KV * S;      // V^T (e, s)
  u16* qh   = p; p += S * D;       // head-major roped Q
  u16* khh  = p; p += S * KV;
  u16* wob  = wqb;                 // alias: wo converted after Q-gemm
  u16* ob   = qraw;                // alias: attn out after rope consumed qraw

  auto cvt_launch = [&](const float* src, u16* dst, size_t n) {
    int n8 = (int)(n / 8);
    int blocks = (n8 + 255) / 256;
    if (blocks > 2048) blocks = 2048;
    cvt_f32_bf16<<<dim3(blocks), dim3(256), 0, stream>>>(src, dst, n8);
  };

  cvt_launch(x, xb, S * D);
  cvt_launch(wq, wqb, D * D);
  cvt_launch(wk, wkb, KV * D);
  cvt_launch(wv, wvb, KV * D);

  // Q = x @ wq^T  (2048x4096x4096)
  gemm_bt<false><<<dim3(D / 128, S / 128), dim3(256), 0, stream>>>(xb, wqb, (void*)qraw,
                                                                   (int)S, (int)D, (int)D);
  // wo conversion reuses wqb space (stream-ordered after Q-gemm)
  cvt_launch(wo, wob, D * D);

  // K = x @ wk^T  (2048x1024x4096)
  gemm_bt<false><<<dim3(KV / 128, S / 128), dim3(256), 0, stream>>>(xb, wkb, (void*)kraw,
                                                                    (int)S, (int)KV, (int)D);
  // V^T = wv @ x^T  (1024x2048x4096) -> coalesced (e,s) output
  gemm_bt<false><<<dim3(S / 128, KV / 128), dim3(256), 0, stream>>>(wvb, xb, (void*)vt,
                                                                    (int)KV, (int)S, (int)D);

  rope_rms<<<dim3((int)(S * 32 / 4)), dim3(256), 0, stream>>>(qraw, qh, fr, 32);
  rope_rms<<<dim3((int)(S * 8 / 4)), dim3(256), 0, stream>>>(kraw, khh, fr, 8);

  attn<<<dim3(32, 32), dim3(256), 0, stream>>>(qh, khh, vt, ob);

  // out = o @ wo^T (2048x4096x4096), fp32 stores
  gemm_bt<true><<<dim3(D / 128, S / 128), dim3(256), 0, stream>>>(ob, wob, (void*)out,
                                                                  (int)S, (int)D, (int)D);
}

// Round 2
// 784.386 us; speedup vs baseline: 1.0585x; 1.0585x over previous
//
#include <hip/hip_runtime.h>
#include <hip/hip_bf16.h>
#include <cstdint>
#include <cstddef>

using u16 = unsigned short;
using u32 = unsigned int;

typedef __attribute__((ext_vector_type(8))) __bf16 bf16x8;
typedef __attribute__((ext_vector_type(4))) float f32x4;
typedef __attribute__((ext_vector_type(2))) float f32x2;
typedef __attribute__((ext_vector_type(4))) u32 u32x4;

typedef const __attribute__((address_space(1))) void* gas_ptr;
typedef __attribute__((address_space(3))) void* las_ptr;

__device__ __forceinline__ void async_cp16(const void* g, void* l) {
  __builtin_amdgcn_global_load_lds((gas_ptr)g, (las_ptr)l, 16, 0, 0);
}

__device__ __forceinline__ float bf2f(u16 u) {
  u32 v = ((u32)u) << 16;
  return __builtin_bit_cast(float, v);
}
__device__ __forceinline__ u16 f2bf(float f) {
  u32 v = __builtin_bit_cast(u32, f);
  u32 r = (v + 0x7fffu + ((v >> 16) & 1u)) >> 16;  // RNE
  return (u16)r;
}

__device__ __forceinline__ f32x4 mfma16(bf16x8 a, bf16x8 b, f32x4 c) {
  return __builtin_amdgcn_mfma_f32_16x16x32_bf16(a, b, c, 0, 0, 0);
}

// ---------------------------------------------------------------- convert
__global__ __launch_bounds__(256) void cvt_f32_bf16(const float* __restrict__ in,
                                                    u16* __restrict__ out, int n8) {
  int i = blockIdx.x * blockDim.x + threadIdx.x;
  int stride = gridDim.x * blockDim.x;
  for (; i < n8; i += stride) {
    const float4* p = (const float4*)(in + (size_t)i * 8);
    float4 a = p[0], b = p[1];
    union { u16 us[8]; u32x4 v; } o;
    o.us[0] = f2bf(a.x); o.us[1] = f2bf(a.y); o.us[2] = f2bf(a.z); o.us[3] = f2bf(a.w);
    o.us[4] = f2bf(b.x); o.us[5] = f2bf(b.y); o.us[6] = f2bf(b.z); o.us[7] = f2bf(b.w);
    *(u32x4*)(out + (size_t)i * 8) = o.v;
  }
}

// ---------------------------------------------------------------- GEMM C = A * B^T
template <bool F32OUT>
__global__ __launch_bounds__(256) void gemm_bt(const u16* __restrict__ A,
                                               const u16* __restrict__ B,
                                               void* __restrict__ Cv,
                                               int M, int N, int K) {
  __shared__ __align__(16) u16 As[128 * 32];
  __shared__ __align__(16) u16 Bs[128 * 32];
  const int tid = threadIdx.x;
  const int wave = tid >> 6, lane = tid & 63;
  const int quad = lane >> 4, c16 = lane & 15;
  const int m0 = blockIdx.y * 128, n0 = blockIdx.x * 128;
  const int wm = (wave & 1) * 64, wn = (wave >> 1) * 64;

  f32x4 acc[4][4] = {};

  const int arow = tid >> 2;
  const int aseg = (tid & 3) ^ ((tid >> 3) & 3);
  const u16* Ab = A + (size_t)m0 * K;
  const u16* Bb = B + (size_t)n0 * K;

  for (int k0 = 0; k0 < K; k0 += 32) {
    __syncthreads();
    async_cp16(Ab + (size_t)arow * K + k0 + aseg * 8, As + (size_t)tid * 8);
    async_cp16(Ab + (size_t)(arow + 64) * K + k0 + aseg * 8, As + (size_t)(tid + 256) * 8);
    async_cp16(Bb + (size_t)arow * K + k0 + aseg * 8, Bs + (size_t)tid * 8);
    async_cp16(Bb + (size_t)(arow + 64) * K + k0 + aseg * 8, Bs + (size_t)(tid + 256) * 8);
    asm volatile("s_waitcnt vmcnt(0)" ::: "memory");
    __syncthreads();

    bf16x8 af[4], bfr[4];
#pragma unroll
    for (int mt = 0; mt < 4; ++mt) {
      int row = wm + mt * 16 + c16;
      int slot = row * 4 + (quad ^ ((row >> 1) & 3));
      af[mt] = *(const bf16x8*)(As + slot * 8);
    }
#pragma unroll
    for (int nt = 0; nt < 4; ++nt) {
      int row = wn + nt * 16 + c16;
      int slot = row * 4 + (quad ^ ((row >> 1) & 3));
      bfr[nt] = *(const bf16x8*)(Bs + slot * 8);
    }
#pragma unroll
    for (int mt = 0; mt < 4; ++mt)
#pragma unroll
      for (int nt = 0; nt < 4; ++nt)
        acc[mt][nt] = mfma16(af[mt], bfr[nt], acc[mt][nt]);
  }

#pragma unroll
  for (int mt = 0; mt < 4; ++mt) {
#pragma unroll
    for (int nt = 0; nt < 4; ++nt) {
#pragma unroll
      for (int r = 0; r < 4; ++r) {
        int gm = m0 + wm + mt * 16 + quad * 4 + r;
        int gn = n0 + wn + nt * 16 + c16;
        float v = acc[mt][nt][r];
        if (F32OUT)
          ((float*)Cv)[(size_t)gm * N + gn] = v;
        else
          ((u16*)Cv)[(size_t)gm * N + gn] = f2bf(v);
      }
    }
  }
}

// ---------------------------------------------------------------- RoPE + RMSNorm
__global__ __launch_bounds__(256) void rope_rms(const u16* __restrict__ in,
                                                u16* __restrict__ out,
                                                const float* __restrict__ freqs,
                                                int n_heads) {
  int gw = blockIdx.x * 4 + (threadIdx.x >> 6);
  int lane = threadIdx.x & 63;
  int s = gw / n_heads, h = gw % n_heads;
  u32 ab = *(const u32*)(in + ((size_t)s * n_heads + h) * 128 + lane * 2);
  float a = bf2f((u16)(ab & 0xffff));
  float b = bf2f((u16)(ab >> 16));
  f32x2 ff = *(const f32x2*)(freqs + (size_t)s * 128 + lane * 2);
  float ra = a * ff.x - b * ff.y;
  float rb = a * ff.y + b * ff.x;
  float ss = ra * ra + rb * rb;
#pragma unroll
  for (int m = 32; m; m >>= 1) ss += __shfl_xor(ss, m, 64);
  float r = rsqrtf(ss * (1.0f / 128.0f) + 1e-5f);
  u32 pk = (u32)f2bf(ra * r) | ((u32)f2bf(rb * r) << 16);
  *(u32*)(out + ((size_t)h * 2048 + s) * 128 + lane * 2) = pk;
}

// ---------------------------------------------------------------- flash attention
// Fixed-max online softmax (scores bounded: |q|=|k|=sqrt(128) after rmsnorm
// -> score*scale <= sqrt(128)=11.32; B=16.5 in log2 domain is safe).
// 128 q rows/block (4 waves x 32), Tk=64. Q:(32,2048,128) K:(8,2048,128)
// VT:(8*128,2048) O:(2048,4096).
#define SEQ 2048
__global__ __launch_bounds__(256) void attn(const u16* __restrict__ Q,
                                            const u16* __restrict__ Kh,
                                            const u16* __restrict__ VT,
                                            u16* __restrict__ O) {
  __shared__ __align__(16) u16 Ks[64 * 128];   // rows t, 16 segs, swz seg^(t&7)
  __shared__ __align__(16) u16 Vs[128 * 64];   // rows d, 8 segs,  swz seg^(d&7)
  __shared__ __align__(16) u16 Ps[4][32 * 64]; // per-wave, rows m, swz seg^(m&7)
  const int tid = threadIdx.x;
  const int wave = tid >> 6, lane = tid & 63;
  const int quad = lane >> 4, c16 = lane & 15;
  const int qb = gridDim.x - 1 - blockIdx.x;  // heavy blocks first
  const int h = blockIdx.y;
  const int hk = h >> 2;
  const int q0b = qb * 128;
  const int q0w = q0b + wave * 32;

  // Q A-fragments: 2 groups of 16 rows, 4 k-chunks each
  bf16x8 qfr[2][4];
  const u16* qbase = Q + (size_t)h * SEQ * 128;
#pragma unroll
  for (int g = 0; g < 2; ++g)
#pragma unroll
    for (int c = 0; c < 4; ++c)
      qfr[g][c] = *(const bf16x8*)(qbase + (size_t)(q0w + g * 16 + c16) * 128 + c * 32 + quad * 8);

  f32x4 o_acc[2][8] = {};
  float lsum[2][4] = {};

  const float sc = 0.12751743f;  // log2(e)/sqrt(128)
  const float B = 16.5f;
  const int t_end = q0b + 128;
  const u16* Kb = Kh + (size_t)hk * SEQ * 128;
  const u16* Vb = VT + (size_t)hk * 128 * SEQ;

  for (int t0 = 0; t0 < t_end; t0 += 64) {
    __syncthreads();
#pragma unroll
    for (int i = 0; i < 4; ++i) {
      int idx = tid + 256 * i;
      int row = idx >> 4, sg = (idx & 15) ^ (row & 7);
      async_cp16(Kb + (size_t)(t0 + row) * 128 + sg * 8, Ks + (size_t)idx * 8);
    }
#pragma unroll
    for (int i = 0; i < 4; ++i) {
      int idx = tid + 256 * i;
      int row = idx >> 3, sg = (idx & 7) ^ (row & 7);
      async_cp16(Vb + (size_t)row * SEQ + t0 + sg * 8, Vs + (size_t)idx * 8);
    }
    asm volatile("s_waitcnt vmcnt(0)" ::: "memory");
    __syncthreads();

    if (t0 < q0w + 32) {  // wave has unmasked work in this tile
      // ---- QK^T: 32 MFMA, 16 K-fragment reads
      f32x4 sa[2][4] = {};
#pragma unroll
      for (int ct = 0; ct < 4; ++ct) {
        int t = ct * 16 + c16;
        int tbase = t * 128;
        int tsw = t & 7;
#pragma unroll
        for (int c = 0; c < 4; ++c) {
          bf16x8 kf = *(const bf16x8*)(Ks + tbase + (((c * 4 + quad) ^ tsw) * 8));
          sa[0][ct] = mfma16(qfr[0][c], kf, sa[0][ct]);
          sa[1][ct] = mfma16(qfr[1][c], kf, sa[1][ct]);
        }
      }

      // ---- fixed-max softmax + pack + P->LDS
      const bool diag = (t0 + 64 > q0w);
      auto soft = [&](bool masked) __attribute__((always_inline)) {
#pragma unroll
        for (int g = 0; g < 2; ++g) {
#pragma unroll
          for (int r = 0; r < 4; ++r) {
            int row = g * 16 + quad * 4 + r;
            int row_q = q0w + row;
            int rbase = row * 64;
            int rsw = row & 7;
#pragma unroll
            for (int ct = 0; ct < 4; ++ct) {
              float s = sa[g][ct][r];
              float arg = fmaf(s, sc, -B);
              if (masked) {
                int t_idx = t0 + ct * 16 + c16;
                arg = (t_idx <= row_q) ? arg : -1.0e30f;
              }
              float p = exp2f(arg);
              lsum[g][r] += p;
              u32 pb = (__builtin_bit_cast(u32, p) + 0x8000u) >> 16;  // round-half-up bf16
              Ps[wave][rbase + (((ct * 2 + (c16 >> 3)) ^ rsw) * 8) + (c16 & 7)] = (u16)pb;
            }
          }
        }
      };
      if (diag) soft(true); else soft(false);
      asm volatile("s_waitcnt lgkmcnt(0)" ::: "memory");

      // ---- P * V: 32 MFMA, 4 P reads + 16 V reads
#pragma unroll
      for (int tc = 0; tc < 2; ++tc) {
        bf16x8 pf[2];
#pragma unroll
        for (int g = 0; g < 2; ++g) {
          int prow = g * 16 + c16;
          pf[g] = *(const bf16x8*)(&Ps[wave][prow * 64 + (((tc * 4 + quad) ^ (prow & 7)) * 8)]);
        }
#pragma unroll
        for (int nt = 0; nt < 8; ++nt) {
          int dl = nt * 16 + c16;
          bf16x8 vf = *(const bf16x8*)(Vs + dl * 64 + (((tc * 4 + quad) ^ (dl & 7)) * 8));
          o_acc[0][nt] = mfma16(pf[0], vf, o_acc[0][nt]);
          o_acc[1][nt] = mfma16(pf[1], vf, o_acc[1][nt]);
        }
      }
    }
  }

  // ---- epilogue: reduce l across the 16 column-lanes, scale, store
#pragma unroll
  for (int g = 0; g < 2; ++g) {
#pragma unroll
    for (int r = 0; r < 4; ++r) {
      float l = lsum[g][r];
#pragma unroll
      for (int m = 1; m < 16; m <<= 1) l += __shfl_xor(l, m, 64);
      float inv = 1.0f / l;
      int s_idx = q0w + g * 16 + quad * 4 + r;
      u16* ob = O + (size_t)s_idx * 4096 + (size_t)h * 128;
#pragma unroll
      for (int nt = 0; nt < 8; ++nt) ob[nt * 16 + c16] = f2bf(o_acc[g][nt][r] * inv);
    }
  }
}

// ---------------------------------------------------------------- launch
extern "C" void kernel_launch(void* const* d_in, const int* in_sizes, int n_in,
                              void* d_out, int out_size, void* d_ws, size_t ws_size,
                              hipStream_t stream) {
  const float* x  = (const float*)d_in[0];
  const float* wq = (const float*)d_in[1];
  const float* wk = (const float*)d_in[2];
  const float* wv = (const float*)d_in[3];
  const float* wo = (const float*)d_in[4];
  const float* fr = (const float*)d_in[5];
  float* out = (float*)d_out;

  const size_t S = 2048, D = 4096, KV = 1024;
  u16* p = (u16*)d_ws;
  u16* xb   = p; p += S * D;
  u16* wqb  = p; p += D * D;
  u16* wkb  = p; p += KV * D;
  u16* wvb  = p; p += KV * D;
  u16* qraw = p; p += S * D;
  u16* kraw = p; p += S * KV;
  u16* vt   = p; p += KV * S;
  u16* qh   = p; p += S * D;
  u16* khh  = p; p += S * KV;
  u16* wob  = wqb;
  u16* ob   = qraw;

  auto cvt_launch = [&](const float* src, u16* dst, size_t n) {
    int n8 = (int)(n / 8);
    int blocks = (n8 + 255) / 256;
    if (blocks > 2048) blocks = 2048;
    cvt_f32_bf16<<<dim3(blocks), dim3(256), 0, stream>>>(src, dst, n8);
  };

  cvt_launch(x, xb, S * D);
  cvt_launch(wq, wqb, D * D);
  cvt_launch(wk, wkb, KV * D);
  cvt_launch(wv, wvb, KV * D);

  gemm_bt<false><<<dim3(D / 128, S / 128), dim3(256), 0, stream>>>(xb, wqb, (void*)qraw,
                                                                   (int)S, (int)D, (int)D);
  cvt_launch(wo, wob, D * D);

  gemm_bt<false><<<dim3(KV / 128, S / 128), dim3(256), 0, stream>>>(xb, wkb, (void*)kraw,
                                                                    (int)S, (int)KV, (int)D);
  gemm_bt<false><<<dim3(S / 128, KV / 128), dim3(256), 0, stream>>>(wvb, xb, (void*)vt,
                                                                    (int)KV, (int)S, (int)D);

  rope_rms<<<dim3((int)(S * 32 / 4)), dim3(256), 0, stream>>>(qraw, qh, fr, 32);
  rope_rms<<<dim3((int)(S * 8 / 4)), dim3(256), 0, stream>>>(kraw, khh, fr, 8);

  attn<<<dim3(16, 32), dim3(256), 0, stream>>>(qh, khh, vt, ob);

  gemm_bt<true><<<dim3(D / 128, S / 128), dim3(256), 0, stream>>>(ob, wob, (void*)out,
                                                                  (int)S, (int)D, (int)D);
}

// Round 3
// 546.088 us; speedup vs baseline: 1.5204x; 1.4364x over previous
//
#include <hip/hip_runtime.h>
#include <hip/hip_bf16.h>
#include <cstdint>
#include <cstddef>

using u16 = unsigned short;
using u32 = unsigned int;

typedef __attribute__((ext_vector_type(8))) __bf16 bf16x8;
typedef __attribute__((ext_vector_type(4))) float f32x4;
typedef __attribute__((ext_vector_type(2))) float f32x2;
typedef __attribute__((ext_vector_type(4))) u32 u32x4;

typedef const __attribute__((address_space(1))) void* gas_ptr;
typedef __attribute__((address_space(3))) void* las_ptr;

__device__ __forceinline__ void async_cp16(const void* g, void* l) {
  __builtin_amdgcn_global_load_lds((gas_ptr)g, (las_ptr)l, 16, 0, 0);
}

__device__ __forceinline__ float bf2f(u16 u) {
  u32 v = ((u32)u) << 16;
  return __builtin_bit_cast(float, v);
}
__device__ __forceinline__ u16 f2bf(float f) {
  u32 v = __builtin_bit_cast(u32, f);
  u32 r = (v + 0x7fffu + ((v >> 16) & 1u)) >> 16;  // RNE
  return (u16)r;
}

__device__ __forceinline__ f32x4 mfma16(bf16x8 a, bf16x8 b, f32x4 c) {
  return __builtin_amdgcn_mfma_f32_16x16x32_bf16(a, b, c, 0, 0, 0);
}

// ---------------------------------------------------------------- convert
__global__ __launch_bounds__(256) void cvt_f32_bf16(const float* __restrict__ in,
                                                    u16* __restrict__ out, int n8) {
  int i = blockIdx.x * blockDim.x + threadIdx.x;
  int stride = gridDim.x * blockDim.x;
  for (; i < n8; i += stride) {
    const float4* p = (const float4*)(in + (size_t)i * 8);
    float4 a = p[0], b = p[1];
    union { u16 us[8]; u32x4 v; } o;
    o.us[0] = f2bf(a.x); o.us[1] = f2bf(a.y); o.us[2] = f2bf(a.z); o.us[3] = f2bf(a.w);
    o.us[4] = f2bf(b.x); o.us[5] = f2bf(b.y); o.us[6] = f2bf(b.z); o.us[7] = f2bf(b.w);
    *(u32x4*)(out + (size_t)i * 8) = o.v;
  }
}

// ---------------------------------------------------------------- GEMM C = A * B^T
template <bool F32OUT>
__global__ __launch_bounds__(256) void gemm_bt(const u16* __restrict__ A,
                                               const u16* __restrict__ B,
                                               void* __restrict__ Cv,
                                               int M, int N, int K) {
  __shared__ __align__(16) u16 As[128 * 32];
  __shared__ __align__(16) u16 Bs[128 * 32];
  const int tid = threadIdx.x;
  const int wave = tid >> 6, lane = tid & 63;
  const int quad = lane >> 4, c16 = lane & 15;
  const int m0 = blockIdx.y * 128, n0 = blockIdx.x * 128;
  const int wm = (wave & 1) * 64, wn = (wave >> 1) * 64;

  f32x4 acc[4][4] = {};

  const int arow = tid >> 2;
  const int aseg = (tid & 3) ^ ((tid >> 3) & 3);
  const u16* Ab = A + (size_t)m0 * K;
  const u16* Bb = B + (size_t)n0 * K;

  for (int k0 = 0; k0 < K; k0 += 32) {
    __syncthreads();
    async_cp16(Ab + (size_t)arow * K + k0 + aseg * 8, As + (size_t)tid * 8);
    async_cp16(Ab + (size_t)(arow + 64) * K + k0 + aseg * 8, As + (size_t)(tid + 256) * 8);
    async_cp16(Bb + (size_t)arow * K + k0 + aseg * 8, Bs + (size_t)tid * 8);
    async_cp16(Bb + (size_t)(arow + 64) * K + k0 + aseg * 8, Bs + (size_t)(tid + 256) * 8);
    asm volatile("s_waitcnt vmcnt(0)" ::: "memory");
    __syncthreads();

    bf16x8 af[4], bfr[4];
#pragma unroll
    for (int mt = 0; mt < 4; ++mt) {
      int row = wm + mt * 16 + c16;
      int slot = row * 4 + (quad ^ ((row >> 1) & 3));
      af[mt] = *(const bf16x8*)(As + slot * 8);
    }
#pragma unroll
    for (int nt = 0; nt < 4; ++nt) {
      int row = wn + nt * 16 + c16;
      int slot = row * 4 + (quad ^ ((row >> 1) & 3));
      bfr[nt] = *(const bf16x8*)(Bs + slot * 8);
    }
#pragma unroll
    for (int mt = 0; mt < 4; ++mt)
#pragma unroll
      for (int nt = 0; nt < 4; ++nt)
        acc[mt][nt] = mfma16(af[mt], bfr[nt], acc[mt][nt]);
  }

#pragma unroll
  for (int mt = 0; mt < 4; ++mt) {
#pragma unroll
    for (int nt = 0; nt < 4; ++nt) {
#pragma unroll
      for (int r = 0; r < 4; ++r) {
        int gm = m0 + wm + mt * 16 + quad * 4 + r;
        int gn = n0 + wn + nt * 16 + c16;
        float v = acc[mt][nt][r];
        if (F32OUT)
          ((float*)Cv)[(size_t)gm * N + gn] = v;
        else
          ((u16*)Cv)[(size_t)gm * N + gn] = f2bf(v);
      }
    }
  }
}

// ---------------------------------------------------------------- V transpose
// in: qkv raw, V block at col 5120, row stride 6144; (2048 s, 1024 e)
// out: vt (1024 e, 2048 s)
__global__ __launch_bounds__(256) void transpose_v(const u16* __restrict__ in,
                                                   u16* __restrict__ out) {
  __shared__ __align__(16) u16 t[64 * 72];
  const int bs = blockIdx.x * 64;  // s block
  const int be = blockIdx.y * 64;  // e block
  const int tid = threadIdx.x;
  {
    const int row = tid >> 3, cc = tid & 7;
#pragma unroll
    for (int pp = 0; pp < 2; ++pp) {
      int r = row + 32 * pp;
      u32x4 v = *(const u32x4*)(in + (size_t)(bs + r) * 6144 + 5120 + be + cc * 8);
      *(u32x4*)(&t[r * 72 + ((cc ^ ((r >> 3) & 7)) * 8)]) = v;
    }
  }
  __syncthreads();
  {
    const int c0 = tid >> 3, rc = tid & 7;
#pragma unroll
    for (int pp = 0; pp < 2; ++pp) {
      int c = c0 + 32 * pp;
      union { u16 us[8]; u32x4 v; } o;
#pragma unroll
      for (int j = 0; j < 8; ++j)
        o.us[j] = t[(rc * 8 + j) * 72 + ((((c >> 3) ^ rc) * 8) + (c & 7))];
      *(u32x4*)(out + (size_t)(be + c) * 2048 + bs + rc * 8) = o.v;
    }
  }
}

// ---------------------------------------------------------------- RoPE + RMSNorm
// in: (s, stride) bf16 at col offset 0; out: (n_heads, 2048, 128) head-major.
__global__ __launch_bounds__(256) void rope_rms(const u16* __restrict__ in, int stride,
                                                u16* __restrict__ out,
                                                const float* __restrict__ freqs,
                                                int n_heads) {
  int gw = blockIdx.x * 4 + (threadIdx.x >> 6);
  int lane = threadIdx.x & 63;
  int s = gw / n_heads, h = gw % n_heads;
  u32 ab = *(const u32*)(in + (size_t)s * stride + h * 128 + lane * 2);
  float a = bf2f((u16)(ab & 0xffff));
  float b = bf2f((u16)(ab >> 16));
  f32x2 ff = *(const f32x2*)(freqs + (size_t)s * 128 + lane * 2);
  float ra = a * ff.x - b * ff.y;
  float rb = a * ff.y + b * ff.x;
  float ss = ra * ra + rb * rb;
#pragma unroll
  for (int m = 32; m; m >>= 1) ss += __shfl_xor(ss, m, 64);
  float r = rsqrtf(ss * (1.0f / 128.0f) + 1e-5f);
  u32 pk = (u32)f2bf(ra * r) | ((u32)f2bf(rb * r) << 16);
  *(u32*)(out + ((size_t)h * 2048 + s) * 128 + lane * 2) = pk;
}

// ---------------------------------------------------------------- flash attention
// Work-balanced folded causal attention, fixed-max softmax, double-buffered K/V.
// Grid: 256 blocks. bid -> hk = bid&7 (XCD-pinned kv head), hq, pair p.
// Block processes q-tiles p and 15-p sequentially: exactly 34 K-steps each.
#define SEQ 2048
__global__ __launch_bounds__(256) void attn(const u16* __restrict__ Q,
                                            const u16* __restrict__ Kh,
                                            const u16* __restrict__ VT,
                                            u16* __restrict__ O) {
  __shared__ __align__(16) u16 Ks[2][64 * 128];   // rows t, 16 segs, swz seg^(t&7)
  __shared__ __align__(16) u16 Vs[2][128 * 64];   // rows d, 8 segs,  swz seg^(d&7)
  __shared__ __align__(16) u16 Ps[4][32 * 64];    // per-wave, rows m, swz seg^(m&7)
  const int tid = threadIdx.x;
  const int wave = tid >> 6, lane = tid & 63;
  const int quad = lane >> 4, c16 = lane & 15;
  const int bid = blockIdx.x;
  const int hk = bid & 7;          // kv head == XCD (round-robin heuristic)
  const int rest = bid >> 3;       // 0..31
  const int hq = rest >> 3;        // 0..3
  const int p = rest & 7;          // 0..7  (pair index)
  const int h = hk * 4 + hq;

  const float sc = 0.12751743f;  // log2(e)/sqrt(128)
  const float B = 16.5f;
  const u16* Kb = Kh + (size_t)hk * SEQ * 128;
  const u16* Vb = VT + (size_t)hk * 128 * SEQ;

  auto stage = [&](int t0, int b) __attribute__((always_inline)) {
#pragma unroll
    for (int i = 0; i < 4; ++i) {
      int idx = tid + 256 * i;
      int row = idx >> 4, sg = (idx & 15) ^ (row & 7);
      async_cp16(Kb + (size_t)(t0 + row) * 128 + sg * 8, &Ks[b][(size_t)idx * 8]);
    }
#pragma unroll
    for (int i = 0; i < 4; ++i) {
      int idx = tid + 256 * i;
      int row = idx >> 3, sg = (idx & 7) ^ (row & 7);
      async_cp16(Vb + (size_t)row * SEQ + t0 + sg * 8, &Vs[b][(size_t)idx * 8]);
    }
  };

#pragma unroll 1
  for (int tile = 0; tile < 2; ++tile) {
    const int qt = tile ? (15 - p) : p;
    const int q0w = qt * 128 + wave * 32;
    const int kend = qt * 128 + 128;

    // Q A-fragments: 2 groups of 16 rows, 4 k-chunks each
    bf16x8 qfr[2][4];
    const u16* qbase = Q + (size_t)h * SEQ * 128;
#pragma unroll
    for (int g = 0; g < 2; ++g)
#pragma unroll
      for (int c = 0; c < 4; ++c)
        qfr[g][c] =
            *(const bf16x8*)(qbase + (size_t)(q0w + g * 16 + c16) * 128 + c * 32 + quad * 8);

    f32x4 o_acc[2][8] = {};
    float lsum[2][4] = {};

    __syncthreads();   // prior tile's reads of buf0 complete
    stage(0, 0);

#pragma unroll 1
    for (int t0 = 0; t0 < kend; t0 += 64) {
      const int cur = (t0 >> 6) & 1;
      asm volatile("s_waitcnt vmcnt(0)" ::: "memory");
      __syncthreads();
      if (t0 + 64 < kend) stage(t0 + 64, cur ^ 1);  // prefetch overlaps compute

      if (t0 < q0w + 32) {  // wave has unmasked work in this tile
        // ---- QK^T: 32 MFMA, 16 K-fragment reads
        f32x4 sa[2][4] = {};
#pragma unroll
        for (int ct = 0; ct < 4; ++ct) {
          int t = ct * 16 + c16;
          int tbase = t * 128;
          int tsw = t & 7;
#pragma unroll
          for (int c = 0; c < 4; ++c) {
            bf16x8 kf = *(const bf16x8*)(&Ks[cur][tbase + (((c * 4 + quad) ^ tsw) * 8)]);
            sa[0][ct] = mfma16(qfr[0][c], kf, sa[0][ct]);
            sa[1][ct] = mfma16(qfr[1][c], kf, sa[1][ct]);
          }
        }

        // ---- fixed-max softmax + pack + P->LDS
        const bool diag = (t0 + 64 > q0w);
        auto soft = [&](bool masked) __attribute__((always_inline)) {
#pragma unroll
          for (int g = 0; g < 2; ++g) {
#pragma unroll
            for (int r = 0; r < 4; ++r) {
              int row = g * 16 + quad * 4 + r;
              int row_q = q0w + row;
              int rbase = row * 64;
              int rsw = row & 7;
#pragma unroll
              for (int ct = 0; ct < 4; ++ct) {
                float s = sa[g][ct][r];
                float arg = fmaf(s, sc, -B);
                if (masked) {
                  int t_idx = t0 + ct * 16 + c16;
                  arg = (t_idx <= row_q) ? arg : -1.0e30f;
                }
                float pe = exp2f(arg);
                lsum[g][r] += pe;
                u32 pb = (__builtin_bit_cast(u32, pe) + 0x8000u) >> 16;
                Ps[wave][rbase + (((ct * 2 + (c16 >> 3)) ^ rsw) * 8) + (c16 & 7)] = (u16)pb;
              }
            }
          }
        };
        if (diag) soft(true); else soft(false);
        asm volatile("s_waitcnt lgkmcnt(0)" ::: "memory");

        // ---- P * V: 32 MFMA, 4 P reads + 16 V reads
#pragma unroll
        for (int tc = 0; tc < 2; ++tc) {
          bf16x8 pf[2];
#pragma unroll
          for (int g = 0; g < 2; ++g) {
            int prow = g * 16 + c16;
            pf[g] = *(const bf16x8*)(&Ps[wave][prow * 64 + (((tc * 4 + quad) ^ (prow & 7)) * 8)]);
          }
#pragma unroll
          for (int nt = 0; nt < 8; ++nt) {
            int dl = nt * 16 + c16;
            bf16x8 vf = *(const bf16x8*)(&Vs[cur][dl * 64 + (((tc * 4 + quad) ^ (dl & 7)) * 8)]);
            o_acc[0][nt] = mfma16(pf[0], vf, o_acc[0][nt]);
            o_acc[1][nt] = mfma16(pf[1], vf, o_acc[1][nt]);
          }
        }
      }
    }

    // ---- epilogue: reduce l across the 16 column-lanes, scale, store
#pragma unroll
    for (int g = 0; g < 2; ++g) {
#pragma unroll
      for (int r = 0; r < 4; ++r) {
        float l = lsum[g][r];
#pragma unroll
        for (int m = 1; m < 16; m <<= 1) l += __shfl_xor(l, m, 64);
        float inv = 1.0f / l;
        int s_idx = q0w + g * 16 + quad * 4 + r;
        u16* ob = O + (size_t)s_idx * 4096 + (size_t)h * 128;
#pragma unroll
        for (int nt = 0; nt < 8; ++nt) ob[nt * 16 + c16] = f2bf(o_acc[g][nt][r] * inv);
      }
    }
  }
}

// ---------------------------------------------------------------- launch
extern "C" void kernel_launch(void* const* d_in, const int* in_sizes, int n_in,
                              void* d_out, int out_size, void* d_ws, size_t ws_size,
                              hipStream_t stream) {
  const float* x  = (const float*)d_in[0];
  const float* wq = (const float*)d_in[1];
  const float* wk = (const float*)d_in[2];
  const float* wv = (const float*)d_in[3];
  const float* wo = (const float*)d_in[4];
  const float* fr = (const float*)d_in[5];
  float* out = (float*)d_out;

  const size_t S = 2048, D = 4096, KV = 1024, NQKV = D + 2 * KV;  // 6144
  u16* p = (u16*)d_ws;
  u16* xb     = p; p += S * D;        // 16 MB
  u16* wqkv   = p; p += NQKV * D;     // 48 MB (wq|wk|wv rows)
  u16* qkvraw = p; p += S * NQKV;     // 24 MB
  u16* qh     = p; p += S * D;        // 16 MB
  u16* khh    = p; p += S * KV;       // 4 MB
  u16* vt     = p; p += KV * S;       // 4 MB
  u16* wob = wqkv;    // alias: wo converted after qkv-gemm
  u16* ob  = qkvraw;  // alias: attn out after rope/transpose consumed qkvraw

  auto cvt_launch = [&](const float* src, u16* dst, size_t n) {
    int n8 = (int)(n / 8);
    int blocks = (n8 + 255) / 256;
    if (blocks > 2048) blocks = 2048;
    cvt_f32_bf16<<<dim3(blocks), dim3(256), 0, stream>>>(src, dst, n8);
  };

  cvt_launch(x, xb, S * D);
  cvt_launch(wq, wqkv, D * D);
  cvt_launch(wk, wqkv + D * D, KV * D);
  cvt_launch(wv, wqkv + (D + KV) * D, KV * D);

  // fused QKV GEMM: (2048 x 6144) = xb @ wqkv^T, 768 blocks
  gemm_bt<false><<<dim3(NQKV / 128, S / 128), dim3(256), 0, stream>>>(
      xb, wqkv, (void*)qkvraw, (int)S, (int)NQKV, (int)D);

  cvt_launch(wo, wob, D * D);  // reuses wqkv space (stream-ordered after gemm)

  transpose_v<<<dim3(32, 16), dim3(256), 0, stream>>>(qkvraw, vt);
  rope_rms<<<dim3((int)(S * 32 / 4)), dim3(256), 0, stream>>>(qkvraw, (int)NQKV, qh, fr, 32);
  rope_rms<<<dim3((int)(S * 8 / 4)), dim3(256), 0, stream>>>(qkvraw + D, (int)NQKV, khh, fr, 8);

  attn<<<dim3(256), dim3(256), 0, stream>>>(qh, khh, vt, ob);

  gemm_bt<true><<<dim3(D / 128, S / 128), dim3(256), 0, stream>>>(ob, wob, (void*)out,
                                                                  (int)S, (int)D, (int)D);
}

// Round 4
// 484.748 us; speedup vs baseline: 1.7128x; 1.1265x over previous
//
#include <hip/hip_runtime.h>
#include <hip/hip_bf16.h>
#include <cstdint>
#include <cstddef>

using u16 = unsigned short;
using u32 = unsigned int;

typedef __attribute__((ext_vector_type(8))) __bf16 bf16x8;
typedef __attribute__((ext_vector_type(4))) float f32x4;
typedef __attribute__((ext_vector_type(2))) float f32x2;
typedef __attribute__((ext_vector_type(4))) u32 u32x4;

typedef const __attribute__((address_space(1))) void* gas_ptr;
typedef __attribute__((address_space(3))) void* las_ptr;

__device__ __forceinline__ void async_cp16(const void* g, void* l) {
  __builtin_amdgcn_global_load_lds((gas_ptr)g, (las_ptr)l, 16, 0, 0);
}

__device__ __forceinline__ float bf2f(u16 u) {
  u32 v = ((u32)u) << 16;
  return __builtin_bit_cast(float, v);
}
__device__ __forceinline__ u16 f2bf(float f) {
  u32 v = __builtin_bit_cast(u32, f);
  u32 r = (v + 0x7fffu + ((v >> 16) & 1u)) >> 16;  // RNE
  return (u16)r;
}

__device__ __forceinline__ f32x4 mfma16(bf16x8 a, bf16x8 b, f32x4 c) {
  return __builtin_amdgcn_mfma_f32_16x16x32_bf16(a, b, c, 0, 0, 0);
}

// ---------------------------------------------------------------- convert
__global__ __launch_bounds__(256) void cvt_f32_bf16(const float* __restrict__ in,
                                                    u16* __restrict__ out, int n8) {
  int i = blockIdx.x * blockDim.x + threadIdx.x;
  int stride = gridDim.x * blockDim.x;
  for (; i < n8; i += stride) {
    const float4* p = (const float4*)(in + (size_t)i * 8);
    float4 a = p[0], b = p[1];
    union { u16 us[8]; u32x4 v; } o;
    o.us[0] = f2bf(a.x); o.us[1] = f2bf(a.y); o.us[2] = f2bf(a.z); o.us[3] = f2bf(a.w);
    o.us[4] = f2bf(b.x); o.us[5] = f2bf(b.y); o.us[6] = f2bf(b.z); o.us[7] = f2bf(b.w);
    *(u32x4*)(out + (size_t)i * 8) = o.v;
  }
}

// ---------------------------------------------------------------- GEMM C = A * B^T
// BK=64: 128x64 LDS tiles (32 KB total), half the barrier drains of BK=32.
// 1D grid, XCD strip swizzle: xcd = bid&7 owns contiguous n-strip, m fastest.
// LDS row = 8 segs of 8 u16; swizzle seg' = seg ^ (row&7).
template <bool F32OUT>
__global__ __launch_bounds__(256, 3) void gemm_bt(const u16* __restrict__ A,
                                                  const u16* __restrict__ B,
                                                  void* __restrict__ Cv,
                                                  int M, int N, int K) {
  __shared__ __align__(16) u16 As[128 * 64];
  __shared__ __align__(16) u16 Bs[128 * 64];
  const int tid = threadIdx.x;
  const int wave = tid >> 6, lane = tid & 63;
  const int quad = lane >> 4, c16 = lane & 15;

  const int mb = M >> 7, nb = N >> 7;
  const int per_xcd_n = nb >> 3;
  const int xcd = blockIdx.x & 7, lid = blockIdx.x >> 3;
  const int m_t = lid % mb, n_local = lid / mb;
  const int m0 = m_t * 128, n0 = (xcd * per_xcd_n + n_local) * 128;

  const int wm = (wave & 1) * 64, wn = (wave >> 1) * 64;

  f32x4 acc[4][4] = {};

  // staging: 1024 chunks per matrix, 4 per thread; row=idx>>3, seg=(idx&7)^(row&7)
  const u16* Ab = A + (size_t)m0 * K;
  const u16* Bb = B + (size_t)n0 * K;

  for (int k0 = 0; k0 < K; k0 += 64) {
    __syncthreads();
#pragma unroll
    for (int i = 0; i < 4; ++i) {
      int idx = tid + 256 * i;
      int row = idx >> 3, sg = (idx & 7) ^ (row & 7);
      async_cp16(Ab + (size_t)row * K + k0 + sg * 8, As + (size_t)idx * 8);
    }
#pragma unroll
    for (int i = 0; i < 4; ++i) {
      int idx = tid + 256 * i;
      int row = idx >> 3, sg = (idx & 7) ^ (row & 7);
      async_cp16(Bb + (size_t)row * K + k0 + sg * 8, Bs + (size_t)idx * 8);
    }
    asm volatile("s_waitcnt vmcnt(0)" ::: "memory");
    __syncthreads();

    bf16x8 af[4][2], bfr[4][2];
#pragma unroll
    for (int mt = 0; mt < 4; ++mt) {
      int row = wm + mt * 16 + c16;
#pragma unroll
      for (int c = 0; c < 2; ++c)
        af[mt][c] = *(const bf16x8*)(As + row * 64 + (((c * 4 + quad) ^ (row & 7)) * 8));
    }
#pragma unroll
    for (int nt = 0; nt < 4; ++nt) {
      int row = wn + nt * 16 + c16;
#pragma unroll
      for (int c = 0; c < 2; ++c)
        bfr[nt][c] = *(const bf16x8*)(Bs + row * 64 + (((c * 4 + quad) ^ (row & 7)) * 8));
    }
#pragma unroll
    for (int c = 0; c < 2; ++c)
#pragma unroll
      for (int mt = 0; mt < 4; ++mt)
#pragma unroll
        for (int nt = 0; nt < 4; ++nt)
          acc[mt][nt] = mfma16(af[mt][c], bfr[nt][c], acc[mt][nt]);
  }

#pragma unroll
  for (int mt = 0; mt < 4; ++mt) {
#pragma unroll
    for (int nt = 0; nt < 4; ++nt) {
#pragma unroll
      for (int r = 0; r < 4; ++r) {
        int gm = m0 + wm + mt * 16 + quad * 4 + r;
        int gn = n0 + wn + nt * 16 + c16;
        float v = acc[mt][nt][r];
        if (F32OUT)
          ((float*)Cv)[(size_t)gm * N + gn] = v;
        else
          ((u16*)Cv)[(size_t)gm * N + gn] = f2bf(v);
      }
    }
  }
}

// ---------------------------------------------------------------- V transpose
__global__ __launch_bounds__(256) void transpose_v(const u16* __restrict__ in,
                                                   u16* __restrict__ out) {
  __shared__ __align__(16) u16 t[64 * 72];
  const int bs = blockIdx.x * 64;
  const int be = blockIdx.y * 64;
  const int tid = threadIdx.x;
  {
    const int row = tid >> 3, cc = tid & 7;
#pragma unroll
    for (int pp = 0; pp < 2; ++pp) {
      int r = row + 32 * pp;
      u32x4 v = *(const u32x4*)(in + (size_t)(bs + r) * 6144 + 5120 + be + cc * 8);
      *(u32x4*)(&t[r * 72 + ((cc ^ ((r >> 3) & 7)) * 8)]) = v;
    }
  }
  __syncthreads();
  {
    const int c0 = tid >> 3, rc = tid & 7;
#pragma unroll
    for (int pp = 0; pp < 2; ++pp) {
      int c = c0 + 32 * pp;
      union { u16 us[8]; u32x4 v; } o;
#pragma unroll
      for (int j = 0; j < 8; ++j)
        o.us[j] = t[(rc * 8 + j) * 72 + ((((c >> 3) ^ rc) * 8) + (c & 7))];
      *(u32x4*)(out + (size_t)(be + c) * 2048 + bs + rc * 8) = o.v;
    }
  }
}

// ---------------------------------------------------------------- RoPE + RMSNorm
__global__ __launch_bounds__(256) void rope_rms(const u16* __restrict__ in, int stride,
                                                u16* __restrict__ out,
                                                const float* __restrict__ freqs,
                                                int n_heads) {
  int gw = blockIdx.x * 4 + (threadIdx.x >> 6);
  int lane = threadIdx.x & 63;
  int s = gw / n_heads, h = gw % n_heads;
  u32 ab = *(const u32*)(in + (size_t)s * stride + h * 128 + lane * 2);
  float a = bf2f((u16)(ab & 0xffff));
  float b = bf2f((u16)(ab >> 16));
  f32x2 ff = *(const f32x2*)(freqs + (size_t)s * 128 + lane * 2);
  float ra = a * ff.x - b * ff.y;
  float rb = a * ff.y + b * ff.x;
  float ss = ra * ra + rb * rb;
#pragma unroll
  for (int m = 32; m; m >>= 1) ss += __shfl_xor(ss, m, 64);
  float r = rsqrtf(ss * (1.0f / 128.0f) + 1e-5f);
  u32 pk = (u32)f2bf(ra * r) | ((u32)f2bf(rb * r) << 16);
  *(u32*)(out + ((size_t)h * 2048 + s) * 128 + lane * 2) = pk;
}

// ---------------------------------------------------------------- flash attention
#define SEQ 2048
__global__ __launch_bounds__(256) void attn(const u16* __restrict__ Q,
                                            const u16* __restrict__ Kh,
                                            const u16* __restrict__ VT,
                                            u16* __restrict__ O) {
  __shared__ __align__(16) u16 Ks[2][64 * 128];
  __shared__ __align__(16) u16 Vs[2][128 * 64];
  __shared__ __align__(16) u16 Ps[4][32 * 64];
  const int tid = threadIdx.x;
  const int wave = tid >> 6, lane = tid & 63;
  const int quad = lane >> 4, c16 = lane & 15;
  const int bid = blockIdx.x;
  const int hk = bid & 7;
  const int rest = bid >> 3;
  const int hq = rest >> 3;
  const int p = rest & 7;
  const int h = hk * 4 + hq;

  const float sc = 0.12751743f;  // log2(e)/sqrt(128)
  const float B = 16.5f;
  const u16* Kb = Kh + (size_t)hk * SEQ * 128;
  const u16* Vb = VT + (size_t)hk * 128 * SEQ;

  auto stage = [&](int t0, int b) __attribute__((always_inline)) {
#pragma unroll
    for (int i = 0; i < 4; ++i) {
      int idx = tid + 256 * i;
      int row = idx >> 4, sg = (idx & 15) ^ (row & 7);
      async_cp16(Kb + (size_t)(t0 + row) * 128 + sg * 8, &Ks[b][(size_t)idx * 8]);
    }
#pragma unroll
    for (int i = 0; i < 4; ++i) {
      int idx = tid + 256 * i;
      int row = idx >> 3, sg = (idx & 7) ^ (row & 7);
      async_cp16(Vb + (size_t)row * SEQ + t0 + sg * 8, &Vs[b][(size_t)idx * 8]);
    }
  };

#pragma unroll 1
  for (int tile = 0; tile < 2; ++tile) {
    const int qt = tile ? (15 - p) : p;
    const int q0w = qt * 128 + wave * 32;
    const int kend = qt * 128 + 128;

    bf16x8 qfr[2][4];
    const u16* qbase = Q + (size_t)h * SEQ * 128;
#pragma unroll
    for (int g = 0; g < 2; ++g)
#pragma unroll
      for (int c = 0; c < 4; ++c)
        qfr[g][c] =
            *(const bf16x8*)(qbase + (size_t)(q0w + g * 16 + c16) * 128 + c * 32 + quad * 8);

    f32x4 o_acc[2][8] = {};
    float lsum[2][4] = {};

    __syncthreads();
    stage(0, 0);

#pragma unroll 1
    for (int t0 = 0; t0 < kend; t0 += 64) {
      const int cur = (t0 >> 6) & 1;
      asm volatile("s_waitcnt vmcnt(0)" ::: "memory");
      __syncthreads();
      if (t0 + 64 < kend) stage(t0 + 64, cur ^ 1);

      if (t0 < q0w + 32) {
        f32x4 sa[2][4] = {};
#pragma unroll
        for (int ct = 0; ct < 4; ++ct) {
          int t = ct * 16 + c16;
          int tbase = t * 128;
          int tsw = t & 7;
#pragma unroll
          for (int c = 0; c < 4; ++c) {
            bf16x8 kf = *(const bf16x8*)(&Ks[cur][tbase + (((c * 4 + quad) ^ tsw) * 8)]);
            sa[0][ct] = mfma16(qfr[0][c], kf, sa[0][ct]);
            sa[1][ct] = mfma16(qfr[1][c], kf, sa[1][ct]);
          }
        }

        const bool diag = (t0 + 64 > q0w);
        auto soft = [&](bool masked) __attribute__((always_inline)) {
#pragma unroll
          for (int g = 0; g < 2; ++g) {
#pragma unroll
            for (int r = 0; r < 4; ++r) {
              int row = g * 16 + quad * 4 + r;
              int row_q = q0w + row;
              int rbase = row * 64;
              int rsw = row & 7;
#pragma unroll
              for (int ct = 0; ct < 4; ++ct) {
                float s = sa[g][ct][r];
                float arg = fmaf(s, sc, -B);
                if (masked) {
                  int t_idx = t0 + ct * 16 + c16;
                  arg = (t_idx <= row_q) ? arg : -1.0e30f;
                }
                float pe = exp2f(arg);
                lsum[g][r] += pe;
                u32 pb = (__builtin_bit_cast(u32, pe) + 0x8000u) >> 16;
                Ps[wave][rbase + (((ct * 2 + (c16 >> 3)) ^ rsw) * 8) + (c16 & 7)] = (u16)pb;
              }
            }
          }
        };
        if (diag) soft(true); else soft(false);
        asm volatile("s_waitcnt lgkmcnt(0)" ::: "memory");

#pragma unroll
        for (int tc = 0; tc < 2; ++tc) {
          bf16x8 pf[2];
#pragma unroll
          for (int g = 0; g < 2; ++g) {
            int prow = g * 16 + c16;
            pf[g] = *(const bf16x8*)(&Ps[wave][prow * 64 + (((tc * 4 + quad) ^ (prow & 7)) * 8)]);
          }
#pragma unroll
          for (int nt = 0; nt < 8; ++nt) {
            int dl = nt * 16 + c16;
            bf16x8 vf = *(const bf16x8*)(&Vs[cur][dl * 64 + (((tc * 4 + quad) ^ (dl & 7)) * 8)]);
            o_acc[0][nt] = mfma16(pf[0], vf, o_acc[0][nt]);
            o_acc[1][nt] = mfma16(pf[1], vf, o_acc[1][nt]);
          }
        }
      }
    }

#pragma unroll
    for (int g = 0; g < 2; ++g) {
#pragma unroll
      for (int r = 0; r < 4; ++r) {
        float l = lsum[g][r];
#pragma unroll
        for (int m = 1; m < 16; m <<= 1) l += __shfl_xor(l, m, 64);
        float inv = 1.0f / l;
        int s_idx = q0w + g * 16 + quad * 4 + r;
        u16* ob = O + (size_t)s_idx * 4096 + (size_t)h * 128;
#pragma unroll
        for (int nt = 0; nt < 8; ++nt) ob[nt * 16 + c16] = f2bf(o_acc[g][nt][r] * inv);
      }
    }
  }
}

// ---------------------------------------------------------------- launch
extern "C" void kernel_launch(void* const* d_in, const int* in_sizes, int n_in,
                              void* d_out, int out_size, void* d_ws, size_t ws_size,
                              hipStream_t stream) {
  const float* x  = (const float*)d_in[0];
  const float* wq = (const float*)d_in[1];
  const float* wk = (const float*)d_in[2];
  const float* wv = (const float*)d_in[3];
  const float* wo = (const float*)d_in[4];
  const float* fr = (const float*)d_in[5];
  float* out = (float*)d_out;

  const size_t S = 2048, D = 4096, KV = 1024, NQKV = D + 2 * KV;  // 6144
  u16* p = (u16*)d_ws;
  u16* xb     = p; p += S * D;
  u16* wqkv   = p; p += NQKV * D;
  u16* qkvraw = p; p += S * NQKV;
  u16* qh     = p; p += S * D;
  u16* khh    = p; p += S * KV;
  u16* vt     = p; p += KV * S;
  u16* wob = wqkv;
  u16* ob  = qkvraw;

  auto cvt_launch = [&](const float* src, u16* dst, size_t n) {
    int n8 = (int)(n / 8);
    int blocks = (n8 + 255) / 256;
    if (blocks > 2048) blocks = 2048;
    cvt_f32_bf16<<<dim3(blocks), dim3(256), 0, stream>>>(src, dst, n8);
  };

  cvt_launch(x, xb, S * D);
  cvt_launch(wq, wqkv, D * D);
  cvt_launch(wk, wqkv + D * D, KV * D);
  cvt_launch(wv, wqkv + (D + KV) * D, KV * D);

  // fused QKV GEMM: (2048 x 6144) = xb @ wqkv^T, 768 blocks (1D, XCD-swizzled)
  gemm_bt<false><<<dim3((S / 128) * (NQKV / 128)), dim3(256), 0, stream>>>(
      xb, wqkv, (void*)qkvraw, (int)S, (int)NQKV, (int)D);

  cvt_launch(wo, wob, D * D);

  transpose_v<<<dim3(32, 16), dim3(256), 0, stream>>>(qkvraw, vt);
  rope_rms<<<dim3((int)(S * 32 / 4)), dim3(256), 0, stream>>>(qkvraw, (int)NQKV, qh, fr, 32);
  rope_rms<<<dim3((int)(S * 8 / 4)), dim3(256), 0, stream>>>(qkvraw + D, (int)NQKV, khh, fr, 8);

  attn<<<dim3(256), dim3(256), 0, stream>>>(qh, khh, vt, ob);

  gemm_bt<true><<<dim3((S / 128) * (D / 128)), dim3(256), 0, stream>>>(
      ob, wob, (void*)out, (int)S, (int)D, (int)D);
}